// Round 3
// baseline (2211.976 us; speedup 1.0000x reference)
//
#include <hip/hip_runtime.h>
#include <math.h>

// Problem constants
#define NB 512
#define NS 17
#define NL 81
#define NV 13030
#define NENC 240
#define NOE 80
#define NPE 60
#define NH 200
#define NIN 380
#define NG 800        // 4*H
#define KP 224        // padded K for h (200->224, mult of 32)
#define KE 256        // padded K for loc_enc (240->256)
#define KO 96         // padded K for order_emb (80->96)
#define NVP 13056     // NV padded to 64 (204*64)
#define NGP 832       // NG padded to 64
#define NBLK 204      // NVP/64 n-blocks in scores grid
#define LDG 840       // LDS row stride for gates staging (fp32 words)

typedef short bf8_t __attribute__((ext_vector_type(8)));   // 8 bf16 (4 VGPRs)
typedef float f4_t __attribute__((ext_vector_type(4)));

__device__ __forceinline__ unsigned short f2bf(float f) {
  unsigned u = __float_as_uint(f);
  unsigned r = (u + 0x7fffu + ((u >> 16) & 1u)) >> 16;
  return (unsigned short)r;
}
__device__ __forceinline__ float bf2f(unsigned short u) {
  return __uint_as_float((unsigned)u << 16);
}

// ---------------- threefry2x32 ----------------
__device__ __host__ __forceinline__ unsigned rotl32h(unsigned x, int d) {
  return (x << d) | (x >> (32 - d));
}
__device__ __host__ __forceinline__ void threefry2x32(
    unsigned k0, unsigned k1, unsigned x0, unsigned x1,
    unsigned& y0, unsigned& y1) {
  unsigned ks2 = k0 ^ k1 ^ 0x1BD11BDAu;
  x0 += k0; x1 += k1;
#define TFR(r) { x0 += x1; x1 = rotl32h(x1, r); x1 ^= x0; }
  TFR(13) TFR(15) TFR(26) TFR(6)
  x0 += k1;  x1 += ks2 + 1u;
  TFR(17) TFR(29) TFR(16) TFR(24)
  x0 += ks2; x1 += k0 + 2u;
  TFR(13) TFR(15) TFR(26) TFR(6)
  x0 += k0;  x1 += k1 + 3u;
  TFR(17) TFR(29) TFR(16) TFR(24)
  x0 += k1;  x1 += ks2 + 4u;
  TFR(13) TFR(15) TFR(26) TFR(6)
  x0 += ks2; x1 += k0 + 5u;
#undef TFR
  y0 = x0; y1 = x1;
}

__device__ __forceinline__ float gumbel_from_bits(unsigned bits) {
  float u = __uint_as_float((bits >> 9) | 0x3f800000u) - 1.0f;
  if (u == 0.0f) u = 1.17549435e-38f;
  return -__logf(-__logf(u));
}

// ---------------- MFMA NT GEMM core: per-wave 16x64 tile --------------------
__device__ __forceinline__ void mfma_nt_16x64(
    const unsigned short* __restrict__ A, const unsigned short* __restrict__ B,
    int lda, int ldb, int m0w, int n0, int nk, f4_t acc[4]) {
  const int lane = threadIdx.x & 63;
  const int tx = lane & 15, quad = lane >> 4;
  const unsigned short* ap = A + (size_t)(m0w + tx) * lda + quad * 8;
  const unsigned short* bp0 = B + (size_t)(n0 + tx) * ldb + quad * 8;
  for (int kc = 0; kc < nk; ++kc) {
    bf8_t a = *(const bf8_t*)(ap + kc * 32);
#pragma unroll
    for (int jf = 0; jf < 4; ++jf) {
      bf8_t b = *(const bf8_t*)(bp0 + (size_t)jf * 16 * ldb + kc * 32);
      acc[jf] = __builtin_amdgcn_mfma_f32_16x16x32_bf16(a, b, acc[jf], 0, 0, 0);
    }
  }
}

// ---------------- prep: bf16 packing of all weight tables ----------------
#define PK_WHH  (NGP * KP)
#define PK_WIHE (NGP * KE)
#define PK_WIHO (NGP * KO)
#define PK_OEB  (NVP * KO)
#define PK_OUTW (NVP * KP)
#define PK_TOT  (PK_WHH + PK_WIHE + PK_WIHO + PK_OEB + PK_OUTW)

__global__ void __launch_bounds__(256) pack_kernel(
    const float* __restrict__ W_hh, const float* __restrict__ W_ih,
    const float* __restrict__ order_embedding, const float* __restrict__ out_W,
    unsigned short* __restrict__ Whh_b, unsigned short* __restrict__ WihEb,
    unsigned short* __restrict__ WihOb, unsigned short* __restrict__ oeb,
    unsigned short* __restrict__ outWb) {
  int t = blockIdx.x * 256 + threadIdx.x;
  if (t >= PK_TOT) return;
  if (t < PK_WHH) {
    int n = t / KP, k = t % KP;
    Whh_b[t] = f2bf((n < NG && k < NH) ? W_hh[n * NH + k] : 0.f);
    return;
  }
  t -= PK_WHH;
  if (t < PK_WIHE) {
    int n = t / KE, k = t % KE;
    WihEb[t] = f2bf((n < NG && k < NENC) ? W_ih[n * NIN + k] : 0.f);
    return;
  }
  t -= PK_WIHE;
  if (t < PK_WIHO) {
    int n = t / KO, k = t % KO;
    WihOb[t] = f2bf((n < NG && k < NOE) ? W_ih[n * NIN + NENC + k] : 0.f);
    return;
  }
  t -= PK_WIHO;
  if (t < PK_OEB) {
    int v = t / KO, k = t % KO;
    oeb[t] = f2bf((v < NV && k < NOE) ? order_embedding[v * NOE + k] : 0.f);
    return;
  }
  t -= PK_OEB;
  {
    int v = t / KP, k = t % KP;
    outWb[t] = f2bf((v < NV && k < NH) ? out_W[v * NH + k] : 0.f);
  }
}

// ---------------- prep: power_emb + invalid ----------------
__global__ void __launch_bounds__(256) misc_kernel(
    const float* __restrict__ power_1h, const float* __restrict__ power_W,
    const float* __restrict__ power_b, const int* __restrict__ loc_idxs,
    float* __restrict__ power_emb, int* __restrict__ invalid) {
  int t = blockIdx.x * 256 + threadIdx.x;
  if (t < NB * NPE) {
    int b = t / NPE, p = t % NPE;
    float a = power_b[p];
#pragma unroll
    for (int k = 0; k < 7; ++k) a = fmaf(power_1h[b * 7 + k], power_W[p * 7 + k], a);
    power_emb[t] = a;
  }
  if (t < NB) {
    bool any = false;
    for (int l = 0; l < NL; ++l) any = any || (loc_idxs[t * NL + l] != -1);
    invalid[t] = any ? 0 : 1;
  }
}

// ---------------- prep: gpow[b][n] = b_ih+b_hh + power_emb[b]@W_ihP.T -------
__global__ void __launch_bounds__(256) gpow_kernel(
    const float* __restrict__ power_emb, const float* __restrict__ W_ih,
    const float* __restrict__ b_ih, const float* __restrict__ b_hh,
    float* __restrict__ gpow) {
  int t = blockIdx.x * 256 + threadIdx.x;
  if (t >= NB * NGP) return;
  int b = t / NGP, n = t % NGP;
  float v = 0.f;
  if (n < NG) {
    v = b_ih[n] + b_hh[n];
    const float* pe = power_emb + b * NPE;
    const float* wp = W_ih + (size_t)n * NIN + NENC + NOE;
    for (int p = 0; p < NPE; ++p) v = fmaf(pe[p], wp[p], v);
  }
  gpow[t] = v;
}

// ---------------- prep: all-step alignment + loc_enc (enc staged in LDS) ----
__global__ void __launch_bounds__(256) lenc_kernel(
    const int* __restrict__ loc_idxs, const float* __restrict__ MA,
    const float* __restrict__ enc, unsigned short* __restrict__ lencb) {
  __shared__ float encs[NL * NENC];   // 77.8 KB
  __shared__ float sel[NL];
  __shared__ float aln[NL];
  __shared__ float denom;
  const int b = blockIdx.x, tid = threadIdx.x;
  for (int i = tid; i < NL * NENC; i += 256) encs[i] = enc[(size_t)b * NL * NENC + i];
  int myloc = (tid < NL) ? loc_idxs[b * NL + tid] : 0;
  __syncthreads();
  for (int s = 0; s < NS; ++s) {
    if (tid < NL) sel[tid] = (myloc == s || myloc == -2) ? 1.0f : 0.0f;
    __syncthreads();
    if (tid < NL) {
      float a = 0.f;
      for (int l = 0; l < NL; ++l) a = fmaf(sel[l], MA[l * NL + tid], a);
      aln[tid] = a;
    }
    __syncthreads();
    if (tid == 0) {
      float d = 0.f;
      for (int l = 0; l < NL; ++l) d += aln[l];
      denom = d;
    }
    __syncthreads();
    if (tid < NL) aln[tid] = (denom != 0.f) ? aln[tid] / denom : 0.0f;
    __syncthreads();
    unsigned short* orow = lencb + ((size_t)b * NS + s) * KE;
    if (tid < KE) {
      float a = 0.f;
      if (tid < NENC) {
        for (int l = 0; l < NL; ++l) a = fmaf(aln[l], encs[l * NENC + tid], a);
      }
      orow[tid] = f2bf(a);
    }
    __syncthreads();
  }
}

// ---- prep: gstat[m=(b,s)][n] = lenc@W_ihE.T + gpow[b]  (bf16 out) ----------
__global__ void __launch_bounds__(256) gstat_kernel(
    const unsigned short* __restrict__ lencb, const unsigned short* __restrict__ WihEb,
    const float* __restrict__ gpow, unsigned short* __restrict__ gstat) {
  const int w = threadIdx.x >> 6;
  const int lane = threadIdx.x & 63;
  const int tx = lane & 15, quad = lane >> 4;
  const int m0w = blockIdx.y * 64 + w * 16;
  const int n0 = blockIdx.x * 64;
  f4_t acc[4] = {};
  mfma_nt_16x64(lencb, WihEb, KE, KE, m0w, n0, KE / 32, acc);
#pragma unroll
  for (int jf = 0; jf < 4; ++jf) {
    int n = n0 + jf * 16 + tx;
#pragma unroll
    for (int reg = 0; reg < 4; ++reg) {
      int m = m0w + quad * 4 + reg;
      int b = m / NS;
      gstat[(size_t)m * NGP + n] = f2bf(acc[jf][reg] + gpow[(size_t)b * NGP + n]);
    }
  }
}

// ---------------- prep: OEG[v][n] = order_embedding[v]@W_ihO.T (bf16) -------
__global__ void __launch_bounds__(256) oeg_kernel(
    const unsigned short* __restrict__ oeb, const unsigned short* __restrict__ WihOb,
    unsigned short* __restrict__ OEG) {
  const int w = threadIdx.x >> 6;
  const int lane = threadIdx.x & 63;
  const int tx = lane & 15, quad = lane >> 4;
  const int m0w = blockIdx.y * 64 + w * 16;
  const int n0 = blockIdx.x * 64;
  f4_t acc[4] = {};
  mfma_nt_16x64(oeb, WihOb, KO, KO, m0w, n0, KO / 32, acc);
#pragma unroll
  for (int jf = 0; jf < 4; ++jf) {
    int n = n0 + jf * 16 + tx;
#pragma unroll
    for (int reg = 0; reg < 4; ++reg) {
      int m = m0w + quad * 4 + reg;
      OEG[(size_t)m * NGP + n] = f2bf(acc[jf][reg]);
    }
  }
}

// ---- per-step: argmax-reduce(prev) + gates MFMA + LSTM cell (fused) --------
// Block owns 16 batch rows. Phase A: reduce pval/pidx of previous scores ->
// sampled idx (write to out), Phase B: h@W_hh.T via MFMA into LDS, Phase C:
// + gstat[b,step] + OEG[idx], LSTM cell, write c (fp32) and h (bf16 -> xh).
__global__ void __launch_bounds__(256) gates_cell_kernel(
    unsigned short* __restrict__ xh, const unsigned short* __restrict__ Whh_b,
    const unsigned short* __restrict__ gstat, const unsigned short* __restrict__ OEG,
    const float* __restrict__ pval, const int* __restrict__ pidx,
    float* __restrict__ c, float* __restrict__ out, int step) {
  __shared__ float gs[16 * LDG];
  __shared__ int sidx[16];
  const int m0 = blockIdx.x * 16;
  const int tid = threadIdx.x;
  // Phase A
  if (step > 0) {
    int r = tid >> 4, sub = tid & 15;
    float bv = -INFINITY; int bi = 0x7fffffff;
    for (int t = sub; t < NBLK; t += 16) {
      float v = pval[(size_t)(m0 + r) * NBLK + t];
      int i = pidx[(size_t)(m0 + r) * NBLK + t];
      if (v > bv || (v == bv && i < bi)) { bv = v; bi = i; }
    }
#pragma unroll
    for (int s = 8; s >= 1; s >>= 1) {
      float ov = __shfl_xor(bv, s);
      int oi = __shfl_xor(bi, s);
      if (ov > bv || (ov == bv && oi < bi)) { bv = ov; bi = oi; }
    }
    if (sub == 0) {
      sidx[r] = bi;
      out[(m0 + r) * NS + step - 1] = (float)bi;
    }
  } else {
    if (tid < 16) sidx[tid] = NV;  // OEG[NV] == 0 (padded rows)
  }
  __syncthreads();
  // Phase B
  const int w = tid >> 6;
  const int lane = tid & 63;
  const int tx = lane & 15, quad = lane >> 4;
  for (int jt = w; jt < NGP / 64; jt += 4) {
    f4_t acc[4] = {};
    mfma_nt_16x64(xh, Whh_b, KP, KP, m0, jt * 64, KP / 32, acc);
#pragma unroll
    for (int jf = 0; jf < 4; ++jf) {
      int n = jt * 64 + jf * 16 + tx;
#pragma unroll
      for (int reg = 0; reg < 4; ++reg)
        gs[(quad * 4 + reg) * LDG + n] = acc[jf][reg];
    }
  }
  __syncthreads();
  // Phase C
  for (int e = tid; e < 16 * NH; e += 256) {
    int r = e / NH, j = e - r * NH;
    int m = m0 + r;
    const float* L = gs + r * LDG;
    size_t gr = ((size_t)m * NS + step) * NGP;
    size_t er = (size_t)sidx[r] * NGP;
    float gi = L[j]          + bf2f(gstat[gr + j])          + bf2f(OEG[er + j]);
    float gf = L[NH + j]     + bf2f(gstat[gr + NH + j])     + bf2f(OEG[er + NH + j]);
    float gg = L[2 * NH + j] + bf2f(gstat[gr + 2 * NH + j]) + bf2f(OEG[er + 2 * NH + j]);
    float go = L[3 * NH + j] + bf2f(gstat[gr + 3 * NH + j]) + bf2f(OEG[er + 3 * NH + j]);
    float si = 1.f / (1.f + __expf(-gi));
    float sf = 1.f / (1.f + __expf(-gf));
    float so = 1.f / (1.f + __expf(-go));
    float tg = fminf(fmaxf(gg, -15.f), 15.f);
    float e2 = __expf(2.f * tg);
    float th = (e2 - 1.f) / (e2 + 1.f);
    float cn = sf * c[(size_t)m * NH + j] + si * th;
    float tc = fminf(fmaxf(cn, -15.f), 15.f);
    float ec = __expf(2.f * tc);
    float hn = so * (ec - 1.f) / (ec + 1.f);
    c[(size_t)m * NH + j] = cn;
    xh[(size_t)m * KP + j] = f2bf(hn);
  }
}

// ------ per-step: scores GEMM + mask + write + gumbel + partial argmax ------
__global__ void __launch_bounds__(256) scores_kernel(
    const unsigned short* __restrict__ xh, const unsigned short* __restrict__ outWb,
    const float* __restrict__ out_b, const int* __restrict__ order_masks,
    const int* __restrict__ invalid, float* __restrict__ out,
    float* __restrict__ pval, int* __restrict__ pidx,
    int step, unsigned k0, unsigned k1) {
  const int w = threadIdx.x >> 6;
  const int lane = threadIdx.x & 63;
  const int tx = lane & 15, quad = lane >> 4;
  const int m0w = blockIdx.y * 64 + w * 16;
  const int n0 = blockIdx.x * 64;
  f4_t acc[4] = {};
  mfma_nt_16x64(xh, outWb, KP, KP, m0w, n0, KP / 32, acc);

  float bias[4];
  int nn[4];
#pragma unroll
  for (int jf = 0; jf < 4; ++jf) {
    nn[jf] = n0 + jf * 16 + tx;
    bias[jf] = (nn[jf] < NV) ? out_b[nn[jf]] : 0.f;
  }

  float bval[4];
  int bidx[4];
#pragma unroll
  for (int reg = 0; reg < 4; ++reg) {
    const int m = m0w + quad * 4 + reg;
    const int inv = invalid[m];
    const int* mrow = order_masks + (size_t)m * NS * NV + (size_t)step * NV;
    float* orow = out + (size_t)NB * NS + ((size_t)m * NS + step) * (size_t)NV;
    float vals[4];
#pragma unroll
    for (int jf = 0; jf < 4; ++jf) {
      int n = nn[jf];
      float v = -1.0e8f;
      if (n < NV) {
        int msk = inv ? 1 : mrow[n];
        v = fminf(acc[jf][reg] + bias[jf], msk ? 9.0e8f : -1.0e8f);
        orow[n] = v;
      }
      vals[jf] = v;
    }
    unsigned base = (unsigned)m * (unsigned)NV;
    unsigned y0, y1, y2, y3;
    threefry2x32(k0, k1, base + (unsigned)nn[0], base + (unsigned)nn[1], y0, y1);
    threefry2x32(k0, k1, base + (unsigned)nn[2], base + (unsigned)nn[3], y2, y3);
    float g[4] = {gumbel_from_bits(y0), gumbel_from_bits(y1),
                  gumbel_from_bits(y2), gumbel_from_bits(y3)};
    float bv = -INFINITY; int bi = 0;
#pragma unroll
    for (int jf = 0; jf < 4; ++jf) {
      float cnd = (nn[jf] < NV) ? vals[jf] + g[jf] : -INFINITY;
      if (cnd > bv) { bv = cnd; bi = nn[jf]; }
    }
    bval[reg] = bv; bidx[reg] = bi;
  }
#pragma unroll
  for (int s = 8; s >= 1; s >>= 1) {
#pragma unroll
    for (int reg = 0; reg < 4; ++reg) {
      float ov = __shfl_xor(bval[reg], s);
      int oi = __shfl_xor(bidx[reg], s);
      if (ov > bval[reg] || (ov == bval[reg] && oi < bidx[reg])) {
        bval[reg] = ov; bidx[reg] = oi;
      }
    }
  }
#pragma unroll
  for (int reg = 0; reg < 4; ++reg) {
    if (tx == reg) {
      int m = m0w + quad * 4 + reg;
      pval[(size_t)m * NBLK + blockIdx.x] = bval[reg];
      pidx[(size_t)m * NBLK + blockIdx.x] = bidx[reg];
    }
  }
}

// ---------------- tail: write last step's sampled idx ----------------
__global__ void __launch_bounds__(256) final_idx_kernel(
    const float* __restrict__ pval, const int* __restrict__ pidx,
    float* __restrict__ out) {
  const int m0 = blockIdx.x * 16;
  const int tid = threadIdx.x;
  int r = tid >> 4, sub = tid & 15;
  float bv = -INFINITY; int bi = 0x7fffffff;
  for (int t = sub; t < NBLK; t += 16) {
    float v = pval[(size_t)(m0 + r) * NBLK + t];
    int i = pidx[(size_t)(m0 + r) * NBLK + t];
    if (v > bv || (v == bv && i < bi)) { bv = v; bi = i; }
  }
#pragma unroll
  for (int s = 8; s >= 1; s >>= 1) {
    float ov = __shfl_xor(bv, s);
    int oi = __shfl_xor(bi, s);
    if (ov > bv || (ov == bv && oi < bi)) { bv = ov; bi = oi; }
  }
  if (sub == 0) out[(m0 + r) * NS + NS - 1] = (float)bi;
}

extern "C" void kernel_launch(void* const* d_in, const int* in_sizes, int n_in,
                              void* d_out, int out_size, void* d_ws, size_t ws_size,
                              hipStream_t stream) {
  const float* enc          = (const float*)d_in[0];
  const int*   loc_idxs     = (const int*)d_in[2];
  const int*   order_masks  = (const int*)d_in[3];
  const float* power_1h     = (const float*)d_in[4];
  const float* order_embedding = (const float*)d_in[5];
  const float* power_W      = (const float*)d_in[6];
  const float* power_b      = (const float*)d_in[7];
  const float* W_ih         = (const float*)d_in[8];
  const float* W_hh         = (const float*)d_in[9];
  const float* b_ih         = (const float*)d_in[10];
  const float* b_hh         = (const float*)d_in[11];
  const float* out_W        = (const float*)d_in[12];
  const float* out_b        = (const float*)d_in[13];
  const float* MA           = (const float*)d_in[14];

  char* p = (char*)d_ws;
  float* c         = (float*)p;            p += (size_t)NB * NH * 4;
  float* pval      = (float*)p;            p += (size_t)NB * NBLK * 4;
  int*   pidx      = (int*)p;              p += (size_t)NB * NBLK * 4;
  int*   invalid   = (int*)p;              p += (size_t)NB * 4;
  float* power_emb = (float*)p;            p += (size_t)NB * NPE * 4;
  float* gpow      = (float*)p;            p += (size_t)NB * NGP * 4;
  unsigned short* xh    = (unsigned short*)p; p += (size_t)NB * KP * 2;
  unsigned short* Whh_b = (unsigned short*)p; p += (size_t)NGP * KP * 2;
  unsigned short* WihEb = (unsigned short*)p; p += (size_t)NGP * KE * 2;
  unsigned short* WihOb = (unsigned short*)p; p += (size_t)NGP * KO * 2;
  unsigned short* oeb   = (unsigned short*)p; p += (size_t)NVP * KO * 2;
  unsigned short* outWb = (unsigned short*)p; p += (size_t)NVP * KP * 2;
  unsigned short* lencb = (unsigned short*)p; p += (size_t)NB * NS * KE * 2;
  unsigned short* gstat = (unsigned short*)p; p += (size_t)NB * NS * NGP * 2;
  unsigned short* OEG   = (unsigned short*)p; p += (size_t)NVP * NGP * 2;

  float* out = (float*)d_out;

  hipMemsetAsync(xh, 0, sizeof(unsigned short) * (size_t)NB * KP, stream);
  hipMemsetAsync(c, 0, sizeof(float) * (size_t)NB * NH, stream);

  pack_kernel<<<(PK_TOT + 255) / 256, 256, 0, stream>>>(
      W_hh, W_ih, order_embedding, out_W, Whh_b, WihEb, WihOb, oeb, outWb);
  misc_kernel<<<(NB * NPE + 255) / 256, 256, 0, stream>>>(
      power_1h, power_W, power_b, loc_idxs, power_emb, invalid);
  gpow_kernel<<<(NB * NGP + 255) / 256, 256, 0, stream>>>(
      power_emb, W_ih, b_ih, b_hh, gpow);
  lenc_kernel<<<NB, 256, 0, stream>>>(loc_idxs, MA, enc, lencb);
  gstat_kernel<<<dim3(NGP / 64, NB * NS / 64), 256, 0, stream>>>(
      lencb, WihEb, gpow, gstat);
  oeg_kernel<<<dim3(NGP / 64, NVP / 64), 256, 0, stream>>>(oeb, WihOb, OEG);

  // step keys (host-side threefry)
  unsigned key[2 * NS];
  for (unsigned i = 0; i < NS; ++i) {
    unsigned y0, y1;
    threefry2x32(0u, 42u, i, i + NS, y0, y1);
    key[2 * i] = y0;
    key[2 * i + 1] = y1;
  }

  dim3 gScores(NBLK, NB / 64);
  for (int s = 0; s < NS; ++s) {
    gates_cell_kernel<<<NB / 16, 256, 0, stream>>>(
        xh, Whh_b, gstat, OEG, pval, pidx, c, out, s);
    scores_kernel<<<gScores, 256, 0, stream>>>(
        xh, outWb, out_b, order_masks, invalid, out, pval, pidx,
        s, key[2 * s], key[2 * s + 1]);
  }
  final_idx_kernel<<<NB / 16, 256, 0, stream>>>(pval, pidx, out);
}